// Round 17
// baseline (294.323 us; speedup 1.0000x reference)
//
#include <hip/hip_runtime.h>
#include <hip/hip_bf16.h>
#include <stdint.h>

// Problem constants
#define Bb 4
#define Tt 1024
#define Hh 16
#define HD 64
#define C3 3072
#define WIN 64  // MEMORY

typedef __bf16 bf16x8 __attribute__((ext_vector_type(8)));
typedef float f32x4 __attribute__((ext_vector_type(4)));

#define MFMA16(a, b, c) __builtin_amdgcn_mfma_f32_16x16x32_bf16((a), (b), (c), 0, 0, 0)

static __device__ __forceinline__ unsigned short f2bf(float f) {
  union { float f; unsigned u; } v; v.f = f;
  unsigned r = (v.u + 0x7FFFu + ((v.u >> 16) & 1u)) >> 16;
  return (unsigned short)r;
}
static __device__ __forceinline__ float bf2f(unsigned short h) {
  union { unsigned u; float f; } v; v.u = ((unsigned)h) << 16;
  return v.f;
}

// ---------------- fused prep: x->bf16 convert + both weight transposes ----------------
__global__ __launch_bounds__(256) void k_prep(const float* __restrict__ x,
                                              const float* __restrict__ Wa,
                                              const float* __restrict__ Wp,
                                              unsigned short* __restrict__ xbf,
                                              unsigned short* __restrict__ WtA,
                                              unsigned short* __restrict__ WtP) {
  __shared__ float tile[32][33];
  const int blk = blockIdx.x;
  const int tid = threadIdx.x;
  if (blk < 4096) {  // convert x (1M float4)
    int i = blk * 256 + tid;
    float4 v = ((const float4*)x)[i];
    ushort4 o;
    o.x = f2bf(v.x); o.y = f2bf(v.y); o.z = f2bf(v.z); o.w = f2bf(v.w);
    ((ushort4*)xbf)[i] = o;
    return;
  }
  const float* Win; unsigned short* Wt; int N, n0, k0;
  if (blk < 7168) { int bb = blk - 4096; Win = Wa; Wt = WtA; N = 3072; n0 = (bb % 96) * 32; k0 = (bb / 96) * 32; }
  else           { int bb = blk - 7168; Win = Wp; Wt = WtP; N = 1024; n0 = (bb % 32) * 32; k0 = (bb / 32) * 32; }
  const int K = 1024;
  int tx = tid & 31, ty = tid >> 5;
  for (int r = ty; r < 32; r += 8)
    tile[r][tx] = Win[(size_t)(k0 + r) * N + n0 + tx];
  __syncthreads();
  for (int r = ty; r < 32; r += 8)
    Wt[(size_t)(n0 + r) * K + k0 + tx] = f2bf(tile[tx][r]);
}

// ------------- bf16 GEMM: C[M][N] = A[M][K] * Bt[N][K]^T  (m97-style, BM x 128 tile) -------------
template <int BM, int BF16_OUT, int SCALEQ>
__global__ __launch_bounds__(256) void k_gemm_bt(const unsigned short* __restrict__ A,
                                                 const unsigned short* __restrict__ Bt,
                                                 void* __restrict__ Cv, int M, int N, int K) {
  constexpr int MI = BM / 32;  // acc row-fragments per wave (4 or 2)
  __shared__ unsigned short lds[BM * 32 + 128 * 32];
  unsigned short* as_ = lds;
  unsigned short* bs_ = lds + BM * 32;
  const int tid = threadIdx.x;
  const int m0 = blockIdx.x * BM, n0 = blockIdx.y * 128;
  const int w = tid >> 6, lane = tid & 63;
  const int wm = (w >> 1) * (BM / 2), wn = (w & 1) * 64;
  const int lrow = lane & 15, lk = lane >> 4;

  f32x4 z = {0.f, 0.f, 0.f, 0.f};
  f32x4 acc[MI][4];
#pragma unroll
  for (int i = 0; i < MI; ++i)
#pragma unroll
    for (int j = 0; j < 4; ++j) acc[i][j] = z;

  const int nk = K >> 5;
  for (int kt = 0; kt < nk; ++kt) {
    const int k0 = kt << 5;
    __syncthreads();
#pragma unroll
    for (int p = 0; p < BM / 64; ++p) {  // A tile
      int seg = tid + p * 256;
      int row = seg >> 2, ks = (seg & 3) << 3;
      __builtin_amdgcn_global_load_lds(
          (__attribute__((address_space(1))) void*)(A + (size_t)(m0 + row) * K + k0 + ks),
          (__attribute__((address_space(3))) void*)(as_ + seg * 8), 16, 0, 0);
    }
#pragma unroll
    for (int p = 0; p < 2; ++p) {        // B tile
      int seg = tid + p * 256;
      int row = seg >> 2, ks = (seg & 3) << 3;
      __builtin_amdgcn_global_load_lds(
          (__attribute__((address_space(1))) void*)(Bt + (size_t)(n0 + row) * K + k0 + ks),
          (__attribute__((address_space(3))) void*)(bs_ + seg * 8), 16, 0, 0);
    }
    __syncthreads();
    bf16x8 af[MI], bfr[4];
#pragma unroll
    for (int f = 0; f < MI; ++f)
      af[f] = *(const bf16x8*)(as_ + (wm + f * 16 + lrow) * 32 + lk * 8);
#pragma unroll
    for (int f = 0; f < 4; ++f)
      bfr[f] = *(const bf16x8*)(bs_ + (wn + f * 16 + lrow) * 32 + lk * 8);
#pragma unroll
    for (int i = 0; i < MI; ++i)
#pragma unroll
      for (int j = 0; j < 4; ++j) acc[i][j] = MFMA16(af[i], bfr[j], acc[i][j]);
  }
  // epilogue: D row = (lane>>4)*4+r, col = lane&15
  const int r0 = lk * 4;
#pragma unroll
  for (int i = 0; i < MI; ++i)
#pragma unroll
    for (int j = 0; j < 4; ++j)
#pragma unroll
      for (int r = 0; r < 4; ++r) {
        int gm = m0 + wm + i * 16 + r0 + r;
        int gn = n0 + wn + j * 16 + lrow;
        float v = acc[i][j][r];
        if (SCALEQ) {
          if (gn < 1024) v *= 0.125f;  // fold 1/sqrt(hd) into q
        }
        if (BF16_OUT)
          ((unsigned short*)Cv)[(size_t)gm * N + gn] = f2bf(v);
        else
          ((float*)Cv)[(size_t)gm * N + gn] = v;
      }
}

// ------------- fused att, 8-wave blocks (R15 structure), VGPR-capped for 2 blocks/CU ----
// __launch_bounds__(512,4): 4 waves/SIMD -> allocator caps at 128 VGPR. Pass2 loads q
// per batch inside the b loop (was a 64-VGPR all-batch preload). Fixed-reference softmax.
__global__ __launch_bounds__(512, 4) void k_att(const unsigned short* __restrict__ qkv,
                                                float* __restrict__ att, float* __restrict__ astd) {
  const int x = blockIdx.x;
  const int ti = (x & 1) ? (x >> 1) : (31 - (x >> 1));  // 31,0,30,1,... pairing
  const int h = blockIdx.y;
  const int i0 = ti * 32;
  const int tid = threadIdx.x;
  const int w = tid >> 6, lane = tid & 63;
  const int lrow = lane & 15, lk = lane >> 4;

  __shared__ float smrh[2][4][32];     // per-half row sums l
  __shared__ float smr[4][32];         // final 1/l
  __shared__ float wbuf[2][8][32][36]; // parity-double-buffered per-WAVE transpose buffers

  // ---- pass 1: wave w -> batch w&3, half w>>2; jt = half, half+2, ... <= ti ----
  {
    const int b1 = w & 3, half = w >> 2;
    const size_t qb_ = ((size_t)(b1 * Tt + i0 + lrow)) * C3 + h * 64 + lk * 8;
    bf16x8 q00 = *(const bf16x8*)(qkv + qb_);
    bf16x8 q01 = *(const bf16x8*)(qkv + qb_ + 32);
    bf16x8 q10 = *(const bf16x8*)(qkv + qb_ + (size_t)16 * C3);
    bf16x8 q11 = *(const bf16x8*)(qkv + qb_ + (size_t)16 * C3 + 32);

    float l[2][4];
#pragma unroll
    for (int i2 = 0; i2 < 2; ++i2)
#pragma unroll
      for (int r = 0; r < 4; ++r) l[i2][r] = 0.f;

    for (int jt = half; jt <= ti; jt += 2) {
      const int j0 = jt * 32;
      const size_t krowa = ((size_t)(b1 * Tt + j0 + lrow)) * C3 + 1024 + h * 64 + lk * 8;
      const size_t krowb = krowa + (size_t)16 * C3;
      bf16x8 k00 = *(const bf16x8*)(qkv + krowa);
      bf16x8 k01 = *(const bf16x8*)(qkv + krowa + 32);
      bf16x8 k10 = *(const bf16x8*)(qkv + krowb);
      bf16x8 k11 = *(const bf16x8*)(qkv + krowb + 32);
      const int ja = j0 + lrow, jb2 = j0 + 16 + lrow;
#pragma unroll
      for (int i2 = 0; i2 < 2; ++i2) {
        bf16x8 qa = i2 ? q10 : q00;
        bf16x8 qb = i2 ? q11 : q01;
        f32x4 sa = {0.f, 0.f, 0.f, 0.f}, sb = {0.f, 0.f, 0.f, 0.f};
        sa = MFMA16(qa, k00, sa);
        sa = MFMA16(qb, k01, sa);
        sb = MFMA16(qa, k10, sb);
        sb = MFMA16(qb, k11, sb);
#pragma unroll
        for (int r = 0; r < 4; ++r) {
          int ig = i0 + i2 * 16 + lk * 4 + r;
          float pa = (ja <= ig) ? __expf(sa[r]) : 0.f;
          float pb = (jb2 <= ig) ? __expf(sb[r]) : 0.f;
          l[i2][r] += pa + pb;  // no loop-carried fmax/rescale chain
        }
      }
    }
    // butterfly SUM across 16-lane lrow groups; publish per-half row sums
#pragma unroll
    for (int i2 = 0; i2 < 2; ++i2)
#pragma unroll
      for (int r = 0; r < 4; ++r) {
        float ll = l[i2][r];
#pragma unroll
        for (int d = 1; d <= 8; d <<= 1) ll += __shfl_xor(ll, d);
        if (lrow == 0) smrh[half][b1][i2 * 16 + lk * 4 + r] = ll;
      }
  }
  __syncthreads();
  // combine halves -> 1/l
  if (tid < 128) {
    int b = tid >> 5, row = tid & 31;
    smr[b][row] = 1.0f / (smrh[0][b][row] + smrh[1][b][row]);
  }
  __syncthreads();

  // ---- pass 2: wave w owns jt = w, w+8, w+16, w+24; q loaded per batch (low VGPR) ----
  const f32x4 z4 = {0.f, 0.f, 0.f, 0.f};
  for (int jt = w; jt < 32; jt += 8) {
    const int j0 = jt * 32;
    if (jt > ti) {  // masked region: pure zero streams (non-temporal)
#pragma unroll
      for (int b = 0; b < 4; ++b)
#pragma unroll
        for (int q = 0; q < 4; ++q) {
          int f = q * 64 + lane;
          int row = f >> 3, c4 = f & 7;
          __builtin_nontemporal_store(
              z4, (f32x4*)&att[(((size_t)(b * Hh + h)) * Tt + i0 + row) * Tt + j0 + c4 * 4]);
        }
#pragma unroll
      for (int q = 0; q < 4; ++q) {
        int f = q * 64 + lane;
        int row = f >> 3, c4 = f & 7;
        __builtin_nontemporal_store(
            z4, (f32x4*)&astd[((size_t)h * Tt + i0 + row) * Tt + j0 + c4 * 4]);
      }
      continue;
    }
    float s1[2][2][4], s2[2][2][4];
#pragma unroll
    for (int i2 = 0; i2 < 2; ++i2)
#pragma unroll
      for (int j2 = 0; j2 < 2; ++j2)
#pragma unroll
        for (int r = 0; r < 4; ++r) { s1[i2][j2][r] = 0.f; s2[i2][j2][r] = 0.f; }

#pragma unroll
    for (int b = 0; b < 4; ++b) {
      float (*wb)[36] = wbuf[b & 1][w];  // parity buffer: batches b and b+2 share; chain depth 2
      // q fragments for THIS batch only (16 VGPR, L2-hot reload)
      const size_t qb_ = ((size_t)(b * Tt + i0 + lrow)) * C3 + h * 64 + lk * 8;
      bf16x8 qf00 = *(const bf16x8*)(qkv + qb_);
      bf16x8 qf01 = *(const bf16x8*)(qkv + qb_ + 32);
      bf16x8 qf10 = *(const bf16x8*)(qkv + qb_ + (size_t)16 * C3);
      bf16x8 qf11 = *(const bf16x8*)(qkv + qb_ + (size_t)16 * C3 + 32);
      const size_t krowa = ((size_t)(b * Tt + j0 + lrow)) * C3 + 1024 + h * 64 + lk * 8;
      const size_t krowb = krowa + (size_t)16 * C3;
      bf16x8 k00 = *(const bf16x8*)(qkv + krowa);
      bf16x8 k01 = *(const bf16x8*)(qkv + krowa + 32);
      bf16x8 k10 = *(const bf16x8*)(qkv + krowb);
      bf16x8 k11 = *(const bf16x8*)(qkv + krowb + 32);
#pragma unroll
      for (int i2 = 0; i2 < 2; ++i2) {
        float rr[4];
#pragma unroll
        for (int r = 0; r < 4; ++r) rr[r] = smr[b][i2 * 16 + lk * 4 + r];
        bf16x8 qa = i2 ? qf10 : qf00;
        bf16x8 qb = i2 ? qf11 : qf01;
#pragma unroll
        for (int j2 = 0; j2 < 2; ++j2) {
          f32x4 s = {0.f, 0.f, 0.f, 0.f};
          s = MFMA16(qa, j2 ? k10 : k00, s);
          s = MFMA16(qb, j2 ? k11 : k01, s);
          const int jg2 = j0 + j2 * 16 + lrow;
#pragma unroll
          for (int r = 0; r < 4; ++r) {
            int ig = i0 + i2 * 16 + lk * 4 + r;
            float p = (jg2 <= ig) ? __expf(s[r]) * rr[r] : 0.f;
            wb[i2 * 16 + lk * 4 + r][j2 * 16 + lrow] = p;
            s1[i2][j2][r] += p;
            s2[i2][j2][r] += p * p;
          }
        }
      }
      // same-wave LDS read-back -> non-temporal float4 att stores for batch b
#pragma unroll
      for (int q = 0; q < 4; ++q) {
        int f = q * 64 + lane;
        int row = f >> 3, c4 = f & 7;
        f32x4 v = *(f32x4*)&wb[row][c4 * 4];
        __builtin_nontemporal_store(
            v, (f32x4*)&att[(((size_t)(b * Hh + h)) * Tt + i0 + row) * Tt + j0 + c4 * 4]);
      }
    }
    // astd: batch moments in-register; transpose via parity-0 buffer
#pragma unroll
    for (int i2 = 0; i2 < 2; ++i2)
#pragma unroll
      for (int j2 = 0; j2 < 2; ++j2)
#pragma unroll
        for (int r = 0; r < 4; ++r) {
          float mean = s1[i2][j2][r] * 0.25f;
          float var = (s2[i2][j2][r] - 4.f * mean * mean) * (1.f / 3.f);
          wbuf[0][w][i2 * 16 + lk * 4 + r][j2 * 16 + lrow] = sqrtf(fmaxf(var, 0.f));
        }
#pragma unroll
    for (int q = 0; q < 4; ++q) {
      int f = q * 64 + lane;
      int row = f >> 3, c4 = f & 7;
      f32x4 v = *(f32x4*)&wbuf[0][w][row][c4 * 4];
      __builtin_nontemporal_store(
          v, (f32x4*)&astd[((size_t)h * Tt + i0 + row) * Tt + j0 + c4 * 4]);
    }
  }
}

// ------------- banded (window=64) softmax @ V  ->  y_heads bf16 [B][T][C] -------------
// (round-1 verbatim, known-good)
__global__ __launch_bounds__(256) void k_bandy(const unsigned short* __restrict__ qkv,
                                               unsigned short* __restrict__ yh) {
  __shared__ unsigned short qls[64 * 66];
  __shared__ unsigned short kls[128 * 66];
  __shared__ unsigned short vls[128 * 66];
  __shared__ float pls[4][80];

  int blk = blockIdx.x;
  int it = blk & 15, h = (blk >> 4) & 15, b = blk >> 8;
  int i0 = it * 64;
  int jb = i0 - 64;
  int tid = threadIdx.x;

  // stage q rows [i0, i0+63], k/v rows [i0-64, i0+63] (row<0 -> zeros)
  for (int r = tid; r < 320; r += 256) {
    unsigned short* dst;
    int grow, sel;
    if (r < 64) { dst = qls + r * 66; grow = i0 + r; sel = 0; }
    else if (r < 192) { dst = kls + (r - 64) * 66; grow = jb + (r - 64); sel = 1; }
    else { dst = vls + (r - 192) * 66; grow = jb + (r - 192); sel = 2; }
    if (grow < 0) {
      for (int t = 0; t < 32; ++t) ((unsigned*)dst)[t] = 0u;
    } else {
      const unsigned* src = (const unsigned*)(qkv + ((size_t)(b * Tt + grow)) * C3 + sel * 1024 + h * 64);
      for (int t = 0; t < 32; ++t) ((unsigned*)dst)[t] = src[t];
    }
  }
  __syncthreads();

  const int w = tid >> 6, lane = tid & 63;
  for (int rr = 0; rr < 16; ++rr) {
    const int i = i0 + (w << 4) + rr;
    const int io = i - i0;
    const int ja = i - 64 + lane;           // key for this lane
    const unsigned* qrow = (const unsigned*)(qls + io * 66);
    const unsigned* krow = (const unsigned*)(kls + (size_t)(io + lane) * 66);
    const unsigned* kerow = (const unsigned*)(kls + (size_t)(io + 64) * 66);  // key j=i
    float sa = 0.f, se = 0.f;
#pragma unroll 8
    for (int t = 0; t < 32; ++t) {
      unsigned qq = qrow[t];
      float q0 = bf2f((unsigned short)qq), q1 = bf2f((unsigned short)(qq >> 16));
      unsigned kk = krow[t];
      sa = fmaf(q0, bf2f((unsigned short)kk), sa);
      sa = fmaf(q1, bf2f((unsigned short)(kk >> 16)), sa);
      unsigned ke = kerow[t];
      se = fmaf(q0, bf2f((unsigned short)ke), se);
      se = fmaf(q1, bf2f((unsigned short)(ke >> 16)), se);
    }
    if (ja < 0) sa = -1e30f;
    float m = sa;
    m = fmaxf(m, __shfl_xor(m, 1));
    m = fmaxf(m, __shfl_xor(m, 2));
    m = fmaxf(m, __shfl_xor(m, 4));
    m = fmaxf(m, __shfl_xor(m, 8));
    m = fmaxf(m, __shfl_xor(m, 16));
    m = fmaxf(m, __shfl_xor(m, 32));
    m = fmaxf(m, se);  // se identical on all lanes
    float pa = __expf(sa - m);
    float pe = __expf(se - m);
    float sum = pa;
    sum += __shfl_xor(sum, 1);
    sum += __shfl_xor(sum, 2);
    sum += __shfl_xor(sum, 4);
    sum += __shfl_xor(sum, 8);
    sum += __shfl_xor(sum, 16);
    sum += __shfl_xor(sum, 32);
    sum += pe;
    float rl = 1.0f / sum;
    pls[w][lane] = pa * rl;
    if (lane == 0) pls[w][64] = pe * rl;
    // PV: lane owns output dim d = lane; keys are idx = io + t, t=0..64
    float y = 0.f;
#pragma unroll 4
    for (int t = 0; t <= 64; ++t)
      y = fmaf(pls[w][t], bf2f(vls[(size_t)(io + t) * 66 + lane]), y);
    yh[((size_t)(b * Tt + i)) * 1024 + h * 64 + lane] = f2bf(y);
  }
}

// ============================ host ============================
extern "C" void kernel_launch(void* const* d_in, const int* in_sizes, int n_in,
                              void* d_out, int out_size, void* d_ws, size_t ws_size,
                              hipStream_t stream) {
  const float* x = (const float*)d_in[0];
  const float* Wa = (const float*)d_in[1];
  const float* Wp = (const float*)d_in[2];

  float* out = (float*)d_out;
  float* y_out = out;                               // [4,1024,1024]
  float* att = out + (size_t)4194304;               // [4,16,1024,1024]
  float* astd = out + (size_t)71303168;             // [16,1024,1024]

  // d_ws scratch: qkv bf16 | y_heads bf16 | WtP bf16   (35.7 MB)
  char* ws = (char*)d_ws;
  unsigned short* qkv = (unsigned short*)ws;                 // 25165824 B
  unsigned short* yh = (unsigned short*)(ws + 25165824);     // 8388608 B
  unsigned short* WtP = (unsigned short*)(ws + 33554432);    // 2097152 B

  // park WtA + x_bf16 inside the y output region (dead until final GEMM writes y)
  char* yreg = (char*)d_out;
  unsigned short* WtA = (unsigned short*)yreg;               // 6291456 B
  unsigned short* xbf = (unsigned short*)(yreg + 6291456);   // 8388608 B

  // fused prep: convert x + transpose both weights (one dispatch)
  k_prep<<<8192, 256, 0, stream>>>(x, Wa, Wp, xbf, WtA, WtP);
  // qkv = x @ W_attn  (q pre-scaled by 1/8), bf16 out
  k_gemm_bt<128, 1, 1><<<dim3(32, 24), 256, 0, stream>>>(xbf, WtA, qkv, 4096, 3072, 1024);
  // fused att: R15 structure, VGPR-capped (launch_bounds 512,4) + per-batch q loads
  k_att<<<dim3(32, 16), 512, 0, stream>>>(qkv, att, astd);
  k_bandy<<<1024, 256, 0, stream>>>(qkv, yh);
  // y = y_heads @ W_proj, fp32 out; BM=64 -> 512 blocks (2/CU)
  k_gemm_bt<64, 0, 0><<<dim3(64, 8), 256, 0, stream>>>(yh, WtP, y_out, 4096, 1024, 1024);
}

// Round 18
// 274.480 us; speedup vs baseline: 1.0723x; 1.0723x over previous
//
#include <hip/hip_runtime.h>
#include <hip/hip_bf16.h>
#include <stdint.h>

// Problem constants
#define Bb 4
#define Tt 1024
#define Hh 16
#define HD 64
#define C3 3072
#define WIN 64  // MEMORY

typedef __bf16 bf16x8 __attribute__((ext_vector_type(8)));
typedef float f32x4 __attribute__((ext_vector_type(4)));

#define MFMA16(a, b, c) __builtin_amdgcn_mfma_f32_16x16x32_bf16((a), (b), (c), 0, 0, 0)

static __device__ __forceinline__ unsigned short f2bf(float f) {
  union { float f; unsigned u; } v; v.f = f;
  unsigned r = (v.u + 0x7FFFu + ((v.u >> 16) & 1u)) >> 16;
  return (unsigned short)r;
}
static __device__ __forceinline__ float bf2f(unsigned short h) {
  union { unsigned u; float f; } v; v.u = ((unsigned)h) << 16;
  return v.f;
}

// ---------------- fused prep: x->bf16 convert + both weight transposes ----------------
__global__ __launch_bounds__(256) void k_prep(const float* __restrict__ x,
                                              const float* __restrict__ Wa,
                                              const float* __restrict__ Wp,
                                              unsigned short* __restrict__ xbf,
                                              unsigned short* __restrict__ WtA,
                                              unsigned short* __restrict__ WtP) {
  __shared__ float tile[32][33];
  const int blk = blockIdx.x;
  const int tid = threadIdx.x;
  if (blk < 4096) {  // convert x (1M float4)
    int i = blk * 256 + tid;
    float4 v = ((const float4*)x)[i];
    ushort4 o;
    o.x = f2bf(v.x); o.y = f2bf(v.y); o.z = f2bf(v.z); o.w = f2bf(v.w);
    ((ushort4*)xbf)[i] = o;
    return;
  }
  const float* Win; unsigned short* Wt; int N, n0, k0;
  if (blk < 7168) { int bb = blk - 4096; Win = Wa; Wt = WtA; N = 3072; n0 = (bb % 96) * 32; k0 = (bb / 96) * 32; }
  else           { int bb = blk - 7168; Win = Wp; Wt = WtP; N = 1024; n0 = (bb % 32) * 32; k0 = (bb / 32) * 32; }
  const int K = 1024;
  int tx = tid & 31, ty = tid >> 5;
  for (int r = ty; r < 32; r += 8)
    tile[r][tx] = Win[(size_t)(k0 + r) * N + n0 + tx];
  __syncthreads();
  for (int r = ty; r < 32; r += 8)
    Wt[(size_t)(n0 + r) * K + k0 + tx] = f2bf(tile[tx][r]);
}

// ------------- bf16 GEMM: C[M][N] = A[M][K] * Bt[N][K]^T  (m97-style, BM x 128 tile) -------------
template <int BM, int BF16_OUT, int SCALEQ>
__global__ __launch_bounds__(256) void k_gemm_bt(const unsigned short* __restrict__ A,
                                                 const unsigned short* __restrict__ Bt,
                                                 void* __restrict__ Cv, int M, int N, int K) {
  constexpr int MI = BM / 32;  // acc row-fragments per wave (4 or 2)
  __shared__ unsigned short lds[BM * 32 + 128 * 32];
  unsigned short* as_ = lds;
  unsigned short* bs_ = lds + BM * 32;
  const int tid = threadIdx.x;
  const int m0 = blockIdx.x * BM, n0 = blockIdx.y * 128;
  const int w = tid >> 6, lane = tid & 63;
  const int wm = (w >> 1) * (BM / 2), wn = (w & 1) * 64;
  const int lrow = lane & 15, lk = lane >> 4;

  f32x4 z = {0.f, 0.f, 0.f, 0.f};
  f32x4 acc[MI][4];
#pragma unroll
  for (int i = 0; i < MI; ++i)
#pragma unroll
    for (int j = 0; j < 4; ++j) acc[i][j] = z;

  const int nk = K >> 5;
  for (int kt = 0; kt < nk; ++kt) {
    const int k0 = kt << 5;
    __syncthreads();
#pragma unroll
    for (int p = 0; p < BM / 64; ++p) {  // A tile
      int seg = tid + p * 256;
      int row = seg >> 2, ks = (seg & 3) << 3;
      __builtin_amdgcn_global_load_lds(
          (__attribute__((address_space(1))) void*)(A + (size_t)(m0 + row) * K + k0 + ks),
          (__attribute__((address_space(3))) void*)(as_ + seg * 8), 16, 0, 0);
    }
#pragma unroll
    for (int p = 0; p < 2; ++p) {        // B tile
      int seg = tid + p * 256;
      int row = seg >> 2, ks = (seg & 3) << 3;
      __builtin_amdgcn_global_load_lds(
          (__attribute__((address_space(1))) void*)(Bt + (size_t)(n0 + row) * K + k0 + ks),
          (__attribute__((address_space(3))) void*)(bs_ + seg * 8), 16, 0, 0);
    }
    __syncthreads();
    bf16x8 af[MI], bfr[4];
#pragma unroll
    for (int f = 0; f < MI; ++f)
      af[f] = *(const bf16x8*)(as_ + (wm + f * 16 + lrow) * 32 + lk * 8);
#pragma unroll
    for (int f = 0; f < 4; ++f)
      bfr[f] = *(const bf16x8*)(bs_ + (wn + f * 16 + lrow) * 32 + lk * 8);
#pragma unroll
    for (int i = 0; i < MI; ++i)
#pragma unroll
      for (int j = 0; j < 4; ++j) acc[i][j] = MFMA16(af[i], bfr[j], acc[i][j]);
  }
  // epilogue: D row = (lane>>4)*4+r, col = lane&15
  const int r0 = lk * 4;
#pragma unroll
  for (int i = 0; i < MI; ++i)
#pragma unroll
    for (int j = 0; j < 4; ++j)
#pragma unroll
      for (int r = 0; r < 4; ++r) {
        int gm = m0 + wm + i * 16 + r0 + r;
        int gn = n0 + wn + j * 16 + lrow;
        float v = acc[i][j][r];
        if (SCALEQ) {
          if (gn < 1024) v *= 0.125f;  // fold 1/sqrt(hd) into q
        }
        if (BF16_OUT)
          ((unsigned short*)Cv)[(size_t)gm * N + gn] = f2bf(v);
        else
          ((float*)Cv)[(size_t)gm * N + gn] = v;
      }
}

// ------------- fused att, 8-wave blocks (R15 structure) + XCD-balanced ti mapping ----
// XCD = blockIdx linear % 8 = x % 8 (gridDim.x=32). XCD c gets ti in {2c, 2c+1, 30-2c, 31-2c}:
// per-XCD work sums equal (62); co-located blocks' K-panel reads are prefix-nested -> one
// K-panel copy per XCD L2 instead of 8-way replication. Fixed-reference softmax (s~N(0,1)).
__global__ __launch_bounds__(512) void k_att(const unsigned short* __restrict__ qkv,
                                             float* __restrict__ att, float* __restrict__ astd) {
  const int x = blockIdx.x;
  const int c = x & 7, slot = x >> 3;
  const int ti = (slot == 0) ? 2 * c : (slot == 1) ? 2 * c + 1 : (slot == 2) ? 30 - 2 * c : 31 - 2 * c;
  const int h = blockIdx.y;
  const int i0 = ti * 32;
  const int tid = threadIdx.x;
  const int w = tid >> 6, lane = tid & 63;
  const int lrow = lane & 15, lk = lane >> 4;

  __shared__ float smrh[2][4][32];     // per-half row sums l
  __shared__ float smr[4][32];         // final 1/l
  __shared__ float wbuf[2][8][32][36]; // parity-double-buffered per-WAVE transpose buffers

  // ---- pass 1: wave w -> batch w&3, half w>>2; jt = half, half+2, ... <= ti ----
  {
    const int b1 = w & 3, half = w >> 2;
    const size_t qb_ = ((size_t)(b1 * Tt + i0 + lrow)) * C3 + h * 64 + lk * 8;
    bf16x8 q00 = *(const bf16x8*)(qkv + qb_);
    bf16x8 q01 = *(const bf16x8*)(qkv + qb_ + 32);
    bf16x8 q10 = *(const bf16x8*)(qkv + qb_ + (size_t)16 * C3);
    bf16x8 q11 = *(const bf16x8*)(qkv + qb_ + (size_t)16 * C3 + 32);

    float l[2][4];
#pragma unroll
    for (int i2 = 0; i2 < 2; ++i2)
#pragma unroll
      for (int r = 0; r < 4; ++r) l[i2][r] = 0.f;

    for (int jt = half; jt <= ti; jt += 2) {
      const int j0 = jt * 32;
      const size_t krowa = ((size_t)(b1 * Tt + j0 + lrow)) * C3 + 1024 + h * 64 + lk * 8;
      const size_t krowb = krowa + (size_t)16 * C3;
      bf16x8 k00 = *(const bf16x8*)(qkv + krowa);
      bf16x8 k01 = *(const bf16x8*)(qkv + krowa + 32);
      bf16x8 k10 = *(const bf16x8*)(qkv + krowb);
      bf16x8 k11 = *(const bf16x8*)(qkv + krowb + 32);
      const int ja = j0 + lrow, jb2 = j0 + 16 + lrow;
#pragma unroll
      for (int i2 = 0; i2 < 2; ++i2) {
        bf16x8 qa = i2 ? q10 : q00;
        bf16x8 qb = i2 ? q11 : q01;
        f32x4 sa = {0.f, 0.f, 0.f, 0.f}, sb = {0.f, 0.f, 0.f, 0.f};
        sa = MFMA16(qa, k00, sa);
        sa = MFMA16(qb, k01, sa);
        sb = MFMA16(qa, k10, sb);
        sb = MFMA16(qb, k11, sb);
#pragma unroll
        for (int r = 0; r < 4; ++r) {
          int ig = i0 + i2 * 16 + lk * 4 + r;
          float pa = (ja <= ig) ? __expf(sa[r]) : 0.f;
          float pb = (jb2 <= ig) ? __expf(sb[r]) : 0.f;
          l[i2][r] += pa + pb;  // no loop-carried fmax/rescale chain
        }
      }
    }
    // butterfly SUM across 16-lane lrow groups; publish per-half row sums
#pragma unroll
    for (int i2 = 0; i2 < 2; ++i2)
#pragma unroll
      for (int r = 0; r < 4; ++r) {
        float ll = l[i2][r];
#pragma unroll
        for (int d = 1; d <= 8; d <<= 1) ll += __shfl_xor(ll, d);
        if (lrow == 0) smrh[half][b1][i2 * 16 + lk * 4 + r] = ll;
      }
  }
  __syncthreads();
  // combine halves -> 1/l
  if (tid < 128) {
    int b = tid >> 5, row = tid & 31;
    smr[b][row] = 1.0f / (smrh[0][b][row] + smrh[1][b][row]);
  }
  __syncthreads();

  // ---- q fragments for ALL batches (static indexing only) ----
  bf16x8 qf[4][2][2];
#pragma unroll
  for (int b = 0; b < 4; ++b) {
    const size_t qb_ = ((size_t)(b * Tt + i0 + lrow)) * C3 + h * 64 + lk * 8;
    qf[b][0][0] = *(const bf16x8*)(qkv + qb_);
    qf[b][0][1] = *(const bf16x8*)(qkv + qb_ + 32);
    qf[b][1][0] = *(const bf16x8*)(qkv + qb_ + (size_t)16 * C3);
    qf[b][1][1] = *(const bf16x8*)(qkv + qb_ + (size_t)16 * C3 + 32);
  }

  // ---- pass 2: wave w owns jt = w, w+8, w+16, w+24 (all 4 batches); no barriers ----
  const f32x4 z4 = {0.f, 0.f, 0.f, 0.f};
  for (int jt = w; jt < 32; jt += 8) {
    const int j0 = jt * 32;
    if (jt > ti) {  // masked region: pure zero streams (non-temporal)
#pragma unroll
      for (int b = 0; b < 4; ++b)
#pragma unroll
        for (int q = 0; q < 4; ++q) {
          int f = q * 64 + lane;
          int row = f >> 3, c4 = f & 7;
          __builtin_nontemporal_store(
              z4, (f32x4*)&att[(((size_t)(b * Hh + h)) * Tt + i0 + row) * Tt + j0 + c4 * 4]);
        }
#pragma unroll
      for (int q = 0; q < 4; ++q) {
        int f = q * 64 + lane;
        int row = f >> 3, c4 = f & 7;
        __builtin_nontemporal_store(
            z4, (f32x4*)&astd[((size_t)h * Tt + i0 + row) * Tt + j0 + c4 * 4]);
      }
      continue;
    }
    float s1[2][2][4], s2[2][2][4];
#pragma unroll
    for (int i2 = 0; i2 < 2; ++i2)
#pragma unroll
      for (int j2 = 0; j2 < 2; ++j2)
#pragma unroll
        for (int r = 0; r < 4; ++r) { s1[i2][j2][r] = 0.f; s2[i2][j2][r] = 0.f; }

#pragma unroll
    for (int b = 0; b < 4; ++b) {
      float (*wb)[36] = wbuf[b & 1][w];  // parity buffer: batches b and b+2 share; chain depth 2
      const size_t krowa = ((size_t)(b * Tt + j0 + lrow)) * C3 + 1024 + h * 64 + lk * 8;
      const size_t krowb = krowa + (size_t)16 * C3;
      bf16x8 k00 = *(const bf16x8*)(qkv + krowa);
      bf16x8 k01 = *(const bf16x8*)(qkv + krowa + 32);
      bf16x8 k10 = *(const bf16x8*)(qkv + krowb);
      bf16x8 k11 = *(const bf16x8*)(qkv + krowb + 32);
#pragma unroll
      for (int i2 = 0; i2 < 2; ++i2) {
        float rr[4];
#pragma unroll
        for (int r = 0; r < 4; ++r) rr[r] = smr[b][i2 * 16 + lk * 4 + r];
#pragma unroll
        for (int j2 = 0; j2 < 2; ++j2) {
          f32x4 s = {0.f, 0.f, 0.f, 0.f};
          s = MFMA16(qf[b][i2][0], j2 ? k10 : k00, s);
          s = MFMA16(qf[b][i2][1], j2 ? k11 : k01, s);
          const int jg2 = j0 + j2 * 16 + lrow;
#pragma unroll
          for (int r = 0; r < 4; ++r) {
            int ig = i0 + i2 * 16 + lk * 4 + r;
            float p = (jg2 <= ig) ? __expf(s[r]) * rr[r] : 0.f;
            wb[i2 * 16 + lk * 4 + r][j2 * 16 + lrow] = p;
            s1[i2][j2][r] += p;
            s2[i2][j2][r] += p * p;
          }
        }
      }
      // same-wave LDS read-back -> non-temporal float4 att stores for batch b
#pragma unroll
      for (int q = 0; q < 4; ++q) {
        int f = q * 64 + lane;
        int row = f >> 3, c4 = f & 7;
        f32x4 v = *(f32x4*)&wb[row][c4 * 4];
        __builtin_nontemporal_store(
            v, (f32x4*)&att[(((size_t)(b * Hh + h)) * Tt + i0 + row) * Tt + j0 + c4 * 4]);
      }
    }
    // astd: batch moments in-register; transpose via parity-0 buffer
#pragma unroll
    for (int i2 = 0; i2 < 2; ++i2)
#pragma unroll
      for (int j2 = 0; j2 < 2; ++j2)
#pragma unroll
        for (int r = 0; r < 4; ++r) {
          float mean = s1[i2][j2][r] * 0.25f;
          float var = (s2[i2][j2][r] - 4.f * mean * mean) * (1.f / 3.f);
          wbuf[0][w][i2 * 16 + lk * 4 + r][j2 * 16 + lrow] = sqrtf(fmaxf(var, 0.f));
        }
#pragma unroll
    for (int q = 0; q < 4; ++q) {
      int f = q * 64 + lane;
      int row = f >> 3, c4 = f & 7;
      f32x4 v = *(f32x4*)&wbuf[0][w][row][c4 * 4];
      __builtin_nontemporal_store(
          v, (f32x4*)&astd[((size_t)h * Tt + i0 + row) * Tt + j0 + c4 * 4]);
    }
  }
}

// ------------- banded (window=64) softmax @ V  ->  y_heads bf16 [B][T][C] -------------
// (round-1 verbatim, known-good)
__global__ __launch_bounds__(256) void k_bandy(const unsigned short* __restrict__ qkv,
                                               unsigned short* __restrict__ yh) {
  __shared__ unsigned short qls[64 * 66];
  __shared__ unsigned short kls[128 * 66];
  __shared__ unsigned short vls[128 * 66];
  __shared__ float pls[4][80];

  int blk = blockIdx.x;
  int it = blk & 15, h = (blk >> 4) & 15, b = blk >> 8;
  int i0 = it * 64;
  int jb = i0 - 64;
  int tid = threadIdx.x;

  // stage q rows [i0, i0+63], k/v rows [i0-64, i0+63] (row<0 -> zeros)
  for (int r = tid; r < 320; r += 256) {
    unsigned short* dst;
    int grow, sel;
    if (r < 64) { dst = qls + r * 66; grow = i0 + r; sel = 0; }
    else if (r < 192) { dst = kls + (r - 64) * 66; grow = jb + (r - 64); sel = 1; }
    else { dst = vls + (r - 192) * 66; grow = jb + (r - 192); sel = 2; }
    if (grow < 0) {
      for (int t = 0; t < 32; ++t) ((unsigned*)dst)[t] = 0u;
    } else {
      const unsigned* src = (const unsigned*)(qkv + ((size_t)(b * Tt + grow)) * C3 + sel * 1024 + h * 64);
      for (int t = 0; t < 32; ++t) ((unsigned*)dst)[t] = src[t];
    }
  }
  __syncthreads();

  const int w = tid >> 6, lane = tid & 63;
  for (int rr = 0; rr < 16; ++rr) {
    const int i = i0 + (w << 4) + rr;
    const int io = i - i0;
    const int ja = i - 64 + lane;           // key for this lane
    const unsigned* qrow = (const unsigned*)(qls + io * 66);
    const unsigned* krow = (const unsigned*)(kls + (size_t)(io + lane) * 66);
    const unsigned* kerow = (const unsigned*)(kls + (size_t)(io + 64) * 66);  // key j=i
    float sa = 0.f, se = 0.f;
#pragma unroll 8
    for (int t = 0; t < 32; ++t) {
      unsigned qq = qrow[t];
      float q0 = bf2f((unsigned short)qq), q1 = bf2f((unsigned short)(qq >> 16));
      unsigned kk = krow[t];
      sa = fmaf(q0, bf2f((unsigned short)kk), sa);
      sa = fmaf(q1, bf2f((unsigned short)(kk >> 16)), sa);
      unsigned ke = kerow[t];
      se = fmaf(q0, bf2f((unsigned short)ke), se);
      se = fmaf(q1, bf2f((unsigned short)(ke >> 16)), se);
    }
    if (ja < 0) sa = -1e30f;
    float m = sa;
    m = fmaxf(m, __shfl_xor(m, 1));
    m = fmaxf(m, __shfl_xor(m, 2));
    m = fmaxf(m, __shfl_xor(m, 4));
    m = fmaxf(m, __shfl_xor(m, 8));
    m = fmaxf(m, __shfl_xor(m, 16));
    m = fmaxf(m, __shfl_xor(m, 32));
    m = fmaxf(m, se);  // se identical on all lanes
    float pa = __expf(sa - m);
    float pe = __expf(se - m);
    float sum = pa;
    sum += __shfl_xor(sum, 1);
    sum += __shfl_xor(sum, 2);
    sum += __shfl_xor(sum, 4);
    sum += __shfl_xor(sum, 8);
    sum += __shfl_xor(sum, 16);
    sum += __shfl_xor(sum, 32);
    sum += pe;
    float rl = 1.0f / sum;
    pls[w][lane] = pa * rl;
    if (lane == 0) pls[w][64] = pe * rl;
    // PV: lane owns output dim d = lane; keys are idx = io + t, t=0..64
    float y = 0.f;
#pragma unroll 4
    for (int t = 0; t <= 64; ++t)
      y = fmaf(pls[w][t], bf2f(vls[(size_t)(io + t) * 66 + lane]), y);
    yh[((size_t)(b * Tt + i)) * 1024 + h * 64 + lane] = f2bf(y);
  }
}

// ============================ host ============================
extern "C" void kernel_launch(void* const* d_in, const int* in_sizes, int n_in,
                              void* d_out, int out_size, void* d_ws, size_t ws_size,
                              hipStream_t stream) {
  const float* x = (const float*)d_in[0];
  const float* Wa = (const float*)d_in[1];
  const float* Wp = (const float*)d_in[2];

  float* out = (float*)d_out;
  float* y_out = out;                               // [4,1024,1024]
  float* att = out + (size_t)4194304;               // [4,16,1024,1024]
  float* astd = out + (size_t)71303168;             // [16,1024,1024]

  // d_ws scratch: qkv bf16 | y_heads bf16 | WtP bf16   (35.7 MB)
  char* ws = (char*)d_ws;
  unsigned short* qkv = (unsigned short*)ws;                 // 25165824 B
  unsigned short* yh = (unsigned short*)(ws + 25165824);     // 8388608 B
  unsigned short* WtP = (unsigned short*)(ws + 33554432);    // 2097152 B

  // park WtA + x_bf16 inside the y output region (dead until final GEMM writes y)
  char* yreg = (char*)d_out;
  unsigned short* WtA = (unsigned short*)yreg;               // 6291456 B
  unsigned short* xbf = (unsigned short*)(yreg + 6291456);   // 8388608 B

  // fused prep: convert x + transpose both weights (one dispatch)
  k_prep<<<8192, 256, 0, stream>>>(x, Wa, Wp, xbf, WtA, WtP);
  // qkv = x @ W_attn  (q pre-scaled by 1/8), bf16 out
  k_gemm_bt<128, 1, 1><<<dim3(32, 24), 256, 0, stream>>>(xbf, WtA, qkv, 4096, 3072, 1024);
  // fused att: R15 structure + XCD-balanced ti mapping
  k_att<<<dim3(32, 16), 512, 0, stream>>>(qkv, att, astd);
  k_bandy<<<1024, 256, 0, stream>>>(qkv, yh);
  // y = y_heads @ W_proj, fp32 out; BM=64 -> 512 blocks (2/CU)
  k_gemm_bt<64, 0, 0><<<dim3(64, 8), 256, 0, stream>>>(yh, WtP, y_out, 4096, 1024, 1024);
}

// Round 19
// 262.631 us; speedup vs baseline: 1.1207x; 1.0451x over previous
//
#include <hip/hip_runtime.h>
#include <hip/hip_bf16.h>
#include <stdint.h>

// Problem constants
#define Bb 4
#define Tt 1024
#define Hh 16
#define HD 64
#define C3 3072
#define WIN 64  // MEMORY

typedef __bf16 bf16x8 __attribute__((ext_vector_type(8)));
typedef float f32x4 __attribute__((ext_vector_type(4)));

#define MFMA16(a, b, c) __builtin_amdgcn_mfma_f32_16x16x32_bf16((a), (b), (c), 0, 0, 0)

static __device__ __forceinline__ unsigned short f2bf(float f) {
  union { float f; unsigned u; } v; v.f = f;
  unsigned r = (v.u + 0x7FFFu + ((v.u >> 16) & 1u)) >> 16;
  return (unsigned short)r;
}
static __device__ __forceinline__ float bf2f(unsigned short h) {
  union { unsigned u; float f; } v; v.u = ((unsigned)h) << 16;
  return v.f;
}

// ---------------- fused prep: x->bf16 convert + both weight transposes ----------------
__global__ __launch_bounds__(256) void k_prep(const float* __restrict__ x,
                                              const float* __restrict__ Wa,
                                              const float* __restrict__ Wp,
                                              unsigned short* __restrict__ xbf,
                                              unsigned short* __restrict__ WtA,
                                              unsigned short* __restrict__ WtP) {
  __shared__ float tile[32][33];
  const int blk = blockIdx.x;
  const int tid = threadIdx.x;
  if (blk < 4096) {  // convert x (1M float4)
    int i = blk * 256 + tid;
    float4 v = ((const float4*)x)[i];
    ushort4 o;
    o.x = f2bf(v.x); o.y = f2bf(v.y); o.z = f2bf(v.z); o.w = f2bf(v.w);
    ((ushort4*)xbf)[i] = o;
    return;
  }
  const float* Win; unsigned short* Wt; int N, n0, k0;
  if (blk < 7168) { int bb = blk - 4096; Win = Wa; Wt = WtA; N = 3072; n0 = (bb % 96) * 32; k0 = (bb / 96) * 32; }
  else           { int bb = blk - 7168; Win = Wp; Wt = WtP; N = 1024; n0 = (bb % 32) * 32; k0 = (bb / 32) * 32; }
  const int K = 1024;
  int tx = tid & 31, ty = tid >> 5;
  for (int r = ty; r < 32; r += 8)
    tile[r][tx] = Win[(size_t)(k0 + r) * N + n0 + tx];
  __syncthreads();
  for (int r = ty; r < 32; r += 8)
    Wt[(size_t)(n0 + r) * K + k0 + tx] = f2bf(tile[tx][r]);
}

// ------------- bf16 GEMM: C[M][N] = A[M][K] * Bt[N][K]^T  (m97-style, BM x 128 tile) -------------
template <int BM, int BF16_OUT, int SCALEQ>
__global__ __launch_bounds__(256) void k_gemm_bt(const unsigned short* __restrict__ A,
                                                 const unsigned short* __restrict__ Bt,
                                                 void* __restrict__ Cv, int M, int N, int K) {
  constexpr int MI = BM / 32;  // acc row-fragments per wave (4 or 2)
  __shared__ unsigned short lds[BM * 32 + 128 * 32];
  unsigned short* as_ = lds;
  unsigned short* bs_ = lds + BM * 32;
  const int tid = threadIdx.x;
  const int m0 = blockIdx.x * BM, n0 = blockIdx.y * 128;
  const int w = tid >> 6, lane = tid & 63;
  const int wm = (w >> 1) * (BM / 2), wn = (w & 1) * 64;
  const int lrow = lane & 15, lk = lane >> 4;

  f32x4 z = {0.f, 0.f, 0.f, 0.f};
  f32x4 acc[MI][4];
#pragma unroll
  for (int i = 0; i < MI; ++i)
#pragma unroll
    for (int j = 0; j < 4; ++j) acc[i][j] = z;

  const int nk = K >> 5;
  for (int kt = 0; kt < nk; ++kt) {
    const int k0 = kt << 5;
    __syncthreads();
#pragma unroll
    for (int p = 0; p < BM / 64; ++p) {  // A tile
      int seg = tid + p * 256;
      int row = seg >> 2, ks = (seg & 3) << 3;
      __builtin_amdgcn_global_load_lds(
          (__attribute__((address_space(1))) void*)(A + (size_t)(m0 + row) * K + k0 + ks),
          (__attribute__((address_space(3))) void*)(as_ + seg * 8), 16, 0, 0);
    }
#pragma unroll
    for (int p = 0; p < 2; ++p) {        // B tile
      int seg = tid + p * 256;
      int row = seg >> 2, ks = (seg & 3) << 3;
      __builtin_amdgcn_global_load_lds(
          (__attribute__((address_space(1))) void*)(Bt + (size_t)(n0 + row) * K + k0 + ks),
          (__attribute__((address_space(3))) void*)(bs_ + seg * 8), 16, 0, 0);
    }
    __syncthreads();
    bf16x8 af[MI], bfr[4];
#pragma unroll
    for (int f = 0; f < MI; ++f)
      af[f] = *(const bf16x8*)(as_ + (wm + f * 16 + lrow) * 32 + lk * 8);
#pragma unroll
    for (int f = 0; f < 4; ++f)
      bfr[f] = *(const bf16x8*)(bs_ + (wn + f * 16 + lrow) * 32 + lk * 8);
#pragma unroll
    for (int i = 0; i < MI; ++i)
#pragma unroll
      for (int j = 0; j < 4; ++j) acc[i][j] = MFMA16(af[i], bfr[j], acc[i][j]);
  }
  // epilogue: D row = (lane>>4)*4+r, col = lane&15
  const int r0 = lk * 4;
#pragma unroll
  for (int i = 0; i < MI; ++i)
#pragma unroll
    for (int j = 0; j < 4; ++j)
#pragma unroll
      for (int r = 0; r < 4; ++r) {
        int gm = m0 + wm + i * 16 + r0 + r;
        int gn = n0 + wn + j * 16 + lrow;
        float v = acc[i][j][r];
        if (SCALEQ) {
          if (gn < 1024) v *= 0.125f;  // fold 1/sqrt(hd) into q
        }
        if (BF16_OUT)
          ((unsigned short*)Cv)[(size_t)gm * N + gn] = f2bf(v);
        else
          ((float*)Cv)[(size_t)gm * N + gn] = v;
      }
}

// ======== merged att (R15-verbatim body) + bandy (512-thread variant), one dispatch ========
// grid 1536, 512 threads. bid%3==0 -> att block g=bid/3 (512 blocks); else bandy (1024).
// LDS union: att needs 75264 B (wbuf-dominated), bandy needs 44800 B -> union = att's
// existing footprint, so merging costs att zero occupancy (fixes R11's failure mode).
__global__ __launch_bounds__(512) void k_attband(const unsigned short* __restrict__ qkv,
                                                 float* __restrict__ att, float* __restrict__ astd,
                                                 unsigned short* __restrict__ yh) {
  __shared__ __align__(16) char smem[75264];
  const int bid = blockIdx.x;
  const int g = bid / 3, rsel = bid - g * 3;
  const int tid = threadIdx.x;
  const int w = tid >> 6, lane = tid & 63;

  if (rsel == 0) {
    // ---------------- att block (R15 verbatim): x = g&31 pairing, h = g>>5 ----------------
    const int x = g & 31;
    const int ti = (x & 1) ? (x >> 1) : (31 - (x >> 1));  // 31,0,30,1,... pairing
    const int h = g >> 5;
    const int i0 = ti * 32;
    const int lrow = lane & 15, lk = lane >> 4;

    float (*smrh)[4][32] = (float(*)[4][32])smem;                  // [2][4][32]
    float (*smr)[32] = (float(*)[32])(smem + 1024);                // [4][32]
    float (*wbuf)[8][32][36] = (float(*)[8][32][36])(smem + 1536); // [2][8][32][36]

    // ---- pass 1: wave w -> batch w&3, half w>>2; jt = half, half+2, ... <= ti ----
    {
      const int b1 = w & 3, half = w >> 2;
      const size_t qb_ = ((size_t)(b1 * Tt + i0 + lrow)) * C3 + h * 64 + lk * 8;
      bf16x8 q00 = *(const bf16x8*)(qkv + qb_);
      bf16x8 q01 = *(const bf16x8*)(qkv + qb_ + 32);
      bf16x8 q10 = *(const bf16x8*)(qkv + qb_ + (size_t)16 * C3);
      bf16x8 q11 = *(const bf16x8*)(qkv + qb_ + (size_t)16 * C3 + 32);

      float l[2][4];
#pragma unroll
      for (int i2 = 0; i2 < 2; ++i2)
#pragma unroll
        for (int r = 0; r < 4; ++r) l[i2][r] = 0.f;

      for (int jt = half; jt <= ti; jt += 2) {
        const int j0 = jt * 32;
        const size_t krowa = ((size_t)(b1 * Tt + j0 + lrow)) * C3 + 1024 + h * 64 + lk * 8;
        const size_t krowb = krowa + (size_t)16 * C3;
        bf16x8 k00 = *(const bf16x8*)(qkv + krowa);
        bf16x8 k01 = *(const bf16x8*)(qkv + krowa + 32);
        bf16x8 k10 = *(const bf16x8*)(qkv + krowb);
        bf16x8 k11 = *(const bf16x8*)(qkv + krowb + 32);
        const int ja = j0 + lrow, jb2 = j0 + 16 + lrow;
#pragma unroll
        for (int i2 = 0; i2 < 2; ++i2) {
          bf16x8 qa = i2 ? q10 : q00;
          bf16x8 qb = i2 ? q11 : q01;
          f32x4 sa = {0.f, 0.f, 0.f, 0.f}, sb = {0.f, 0.f, 0.f, 0.f};
          sa = MFMA16(qa, k00, sa);
          sa = MFMA16(qb, k01, sa);
          sb = MFMA16(qa, k10, sb);
          sb = MFMA16(qb, k11, sb);
#pragma unroll
          for (int r = 0; r < 4; ++r) {
            int ig = i0 + i2 * 16 + lk * 4 + r;
            float pa = (ja <= ig) ? __expf(sa[r]) : 0.f;
            float pb = (jb2 <= ig) ? __expf(sb[r]) : 0.f;
            l[i2][r] += pa + pb;  // no loop-carried fmax/rescale chain
          }
        }
      }
      // butterfly SUM across 16-lane lrow groups; publish per-half row sums
#pragma unroll
      for (int i2 = 0; i2 < 2; ++i2)
#pragma unroll
        for (int r = 0; r < 4; ++r) {
          float ll = l[i2][r];
#pragma unroll
          for (int d = 1; d <= 8; d <<= 1) ll += __shfl_xor(ll, d);
          if (lrow == 0) smrh[half][b1][i2 * 16 + lk * 4 + r] = ll;
        }
    }
    __syncthreads();
    // combine halves -> 1/l
    if (tid < 128) {
      int b = tid >> 5, row = tid & 31;
      smr[b][row] = 1.0f / (smrh[0][b][row] + smrh[1][b][row]);
    }
    __syncthreads();

    // ---- q fragments for ALL batches (static indexing only) ----
    bf16x8 qf[4][2][2];
#pragma unroll
    for (int b = 0; b < 4; ++b) {
      const size_t qb_ = ((size_t)(b * Tt + i0 + lrow)) * C3 + h * 64 + lk * 8;
      qf[b][0][0] = *(const bf16x8*)(qkv + qb_);
      qf[b][0][1] = *(const bf16x8*)(qkv + qb_ + 32);
      qf[b][1][0] = *(const bf16x8*)(qkv + qb_ + (size_t)16 * C3);
      qf[b][1][1] = *(const bf16x8*)(qkv + qb_ + (size_t)16 * C3 + 32);
    }

    // ---- pass 2: wave w owns jt = w, w+8, w+16, w+24 (all 4 batches); no barriers ----
    const f32x4 z4 = {0.f, 0.f, 0.f, 0.f};
    for (int jt = w; jt < 32; jt += 8) {
      const int j0 = jt * 32;
      if (jt > ti) {  // masked region: pure zero streams (non-temporal)
#pragma unroll
        for (int b = 0; b < 4; ++b)
#pragma unroll
          for (int q = 0; q < 4; ++q) {
            int f = q * 64 + lane;
            int row = f >> 3, c4 = f & 7;
            __builtin_nontemporal_store(
                z4, (f32x4*)&att[(((size_t)(b * Hh + h)) * Tt + i0 + row) * Tt + j0 + c4 * 4]);
          }
#pragma unroll
        for (int q = 0; q < 4; ++q) {
          int f = q * 64 + lane;
          int row = f >> 3, c4 = f & 7;
          __builtin_nontemporal_store(
              z4, (f32x4*)&astd[((size_t)h * Tt + i0 + row) * Tt + j0 + c4 * 4]);
        }
        continue;
      }
      float s1[2][2][4], s2[2][2][4];
#pragma unroll
      for (int i2 = 0; i2 < 2; ++i2)
#pragma unroll
        for (int j2 = 0; j2 < 2; ++j2)
#pragma unroll
          for (int r = 0; r < 4; ++r) { s1[i2][j2][r] = 0.f; s2[i2][j2][r] = 0.f; }

#pragma unroll
      for (int b = 0; b < 4; ++b) {
        float (*wb)[36] = wbuf[b & 1][w];  // parity buffer: chain depth 2
        const size_t krowa = ((size_t)(b * Tt + j0 + lrow)) * C3 + 1024 + h * 64 + lk * 8;
        const size_t krowb = krowa + (size_t)16 * C3;
        bf16x8 k00 = *(const bf16x8*)(qkv + krowa);
        bf16x8 k01 = *(const bf16x8*)(qkv + krowa + 32);
        bf16x8 k10 = *(const bf16x8*)(qkv + krowb);
        bf16x8 k11 = *(const bf16x8*)(qkv + krowb + 32);
#pragma unroll
        for (int i2 = 0; i2 < 2; ++i2) {
          float rr[4];
#pragma unroll
          for (int r = 0; r < 4; ++r) rr[r] = smr[b][i2 * 16 + lk * 4 + r];
#pragma unroll
          for (int j2 = 0; j2 < 2; ++j2) {
            f32x4 s = {0.f, 0.f, 0.f, 0.f};
            s = MFMA16(qf[b][i2][0], j2 ? k10 : k00, s);
            s = MFMA16(qf[b][i2][1], j2 ? k11 : k01, s);
            const int jg2 = j0 + j2 * 16 + lrow;
#pragma unroll
            for (int r = 0; r < 4; ++r) {
              int ig = i0 + i2 * 16 + lk * 4 + r;
              float p = (jg2 <= ig) ? __expf(s[r]) * rr[r] : 0.f;
              wb[i2 * 16 + lk * 4 + r][j2 * 16 + lrow] = p;
              s1[i2][j2][r] += p;
              s2[i2][j2][r] += p * p;
            }
          }
        }
        // same-wave LDS read-back -> non-temporal float4 att stores for batch b
#pragma unroll
        for (int q = 0; q < 4; ++q) {
          int f = q * 64 + lane;
          int row = f >> 3, c4 = f & 7;
          f32x4 v = *(f32x4*)&wb[row][c4 * 4];
          __builtin_nontemporal_store(
              v, (f32x4*)&att[(((size_t)(b * Hh + h)) * Tt + i0 + row) * Tt + j0 + c4 * 4]);
        }
      }
      // astd: batch moments in-register; transpose via parity-0 buffer
#pragma unroll
      for (int i2 = 0; i2 < 2; ++i2)
#pragma unroll
        for (int j2 = 0; j2 < 2; ++j2)
#pragma unroll
          for (int r = 0; r < 4; ++r) {
            float mean = s1[i2][j2][r] * 0.25f;
            float var = (s2[i2][j2][r] - 4.f * mean * mean) * (1.f / 3.f);
            wbuf[0][w][i2 * 16 + lk * 4 + r][j2 * 16 + lrow] = sqrtf(fmaxf(var, 0.f));
          }
#pragma unroll
      for (int q = 0; q < 4; ++q) {
        int f = q * 64 + lane;
        int row = f >> 3, c4 = f & 7;
        f32x4 v = *(f32x4*)&wbuf[0][w][row][c4 * 4];
        __builtin_nontemporal_store(
            v, (f32x4*)&astd[((size_t)h * Tt + i0 + row) * Tt + j0 + c4 * 4]);
      }
    }
    return;
  }

  // ---------------- bandy block (R1 body at 512 threads: 8 waves x 8 rows) ----------------
  {
    const int blk = 2 * g + (rsel - 1);
    unsigned short* qls = (unsigned short*)smem;          // 64*66
    unsigned short* kls = qls + 64 * 66;                  // 128*66
    unsigned short* vls = kls + 128 * 66;                 // 128*66
    float (*pls)[80] = (float(*)[80])(smem + (64 + 128 + 128) * 66 * 2);  // [8][80]

    int it = blk & 15, h = (blk >> 4) & 15, b = blk >> 8;
    int i0 = it * 64;
    int jb = i0 - 64;

    for (int r = tid; r < 320; r += 512) {
      unsigned short* dst;
      int grow, sel;
      if (r < 64) { dst = qls + r * 66; grow = i0 + r; sel = 0; }
      else if (r < 192) { dst = kls + (r - 64) * 66; grow = jb + (r - 64); sel = 1; }
      else { dst = vls + (r - 192) * 66; grow = jb + (r - 192); sel = 2; }
      if (grow < 0) {
        for (int t = 0; t < 32; ++t) ((unsigned*)dst)[t] = 0u;
      } else {
        const unsigned* src = (const unsigned*)(qkv + ((size_t)(b * Tt + grow)) * C3 + sel * 1024 + h * 64);
        for (int t = 0; t < 32; ++t) ((unsigned*)dst)[t] = src[t];
      }
    }
    __syncthreads();

    for (int rr = 0; rr < 8; ++rr) {
      const int i = i0 + (w << 3) + rr;
      const int io = i - i0;
      const int ja = i - 64 + lane;
      const unsigned* qrow = (const unsigned*)(qls + io * 66);
      const unsigned* krow = (const unsigned*)(kls + (size_t)(io + lane) * 66);
      const unsigned* kerow = (const unsigned*)(kls + (size_t)(io + 64) * 66);
      float sa = 0.f, se = 0.f;
#pragma unroll 8
      for (int t = 0; t < 32; ++t) {
        unsigned qq = qrow[t];
        float q0 = bf2f((unsigned short)qq), q1 = bf2f((unsigned short)(qq >> 16));
        unsigned kk = krow[t];
        sa = fmaf(q0, bf2f((unsigned short)kk), sa);
        sa = fmaf(q1, bf2f((unsigned short)(kk >> 16)), sa);
        unsigned ke = kerow[t];
        se = fmaf(q0, bf2f((unsigned short)ke), se);
        se = fmaf(q1, bf2f((unsigned short)(ke >> 16)), se);
      }
      if (ja < 0) sa = -1e30f;
      float m = sa;
      m = fmaxf(m, __shfl_xor(m, 1));
      m = fmaxf(m, __shfl_xor(m, 2));
      m = fmaxf(m, __shfl_xor(m, 4));
      m = fmaxf(m, __shfl_xor(m, 8));
      m = fmaxf(m, __shfl_xor(m, 16));
      m = fmaxf(m, __shfl_xor(m, 32));
      m = fmaxf(m, se);
      float pa = __expf(sa - m);
      float pe = __expf(se - m);
      float sum = pa;
      sum += __shfl_xor(sum, 1);
      sum += __shfl_xor(sum, 2);
      sum += __shfl_xor(sum, 4);
      sum += __shfl_xor(sum, 8);
      sum += __shfl_xor(sum, 16);
      sum += __shfl_xor(sum, 32);
      sum += pe;
      float rl = 1.0f / sum;
      pls[w][lane] = pa * rl;
      if (lane == 0) pls[w][64] = pe * rl;
      float y = 0.f;
#pragma unroll 4
      for (int t = 0; t <= 64; ++t)
        y = fmaf(pls[w][t], bf2f(vls[(size_t)(io + t) * 66 + lane]), y);
      yh[((size_t)(b * Tt + i)) * 1024 + h * 64 + lane] = f2bf(y);
    }
  }
}

// ============================ host ============================
extern "C" void kernel_launch(void* const* d_in, const int* in_sizes, int n_in,
                              void* d_out, int out_size, void* d_ws, size_t ws_size,
                              hipStream_t stream) {
  const float* x = (const float*)d_in[0];
  const float* Wa = (const float*)d_in[1];
  const float* Wp = (const float*)d_in[2];

  float* out = (float*)d_out;
  float* y_out = out;                               // [4,1024,1024]
  float* att = out + (size_t)4194304;               // [4,16,1024,1024]
  float* astd = out + (size_t)71303168;             // [16,1024,1024]

  // d_ws scratch: qkv bf16 | y_heads bf16 | WtP bf16   (35.7 MB)
  char* ws = (char*)d_ws;
  unsigned short* qkv = (unsigned short*)ws;                 // 25165824 B
  unsigned short* yh = (unsigned short*)(ws + 25165824);     // 8388608 B
  unsigned short* WtP = (unsigned short*)(ws + 33554432);    // 2097152 B

  // park WtA + x_bf16 inside the y output region (dead until final GEMM writes y)
  char* yreg = (char*)d_out;
  unsigned short* WtA = (unsigned short*)yreg;               // 6291456 B
  unsigned short* xbf = (unsigned short*)(yreg + 6291456);   // 8388608 B

  // fused prep: convert x + transpose both weights (one dispatch)
  k_prep<<<8192, 256, 0, stream>>>(x, Wa, Wp, xbf, WtA, WtP);
  // qkv = x @ W_attn  (q pre-scaled by 1/8), bf16 out
  k_gemm_bt<128, 1, 1><<<dim3(32, 24), 256, 0, stream>>>(xbf, WtA, qkv, 4096, 3072, 1024);
  // merged att (R15 structure) + bandy, interleaved, union LDS = att's own footprint
  k_attband<<<1536, 512, 0, stream>>>(qkv, att, astd, yh);
  // y = y_heads @ W_proj, fp32 out; BM=64 -> 512 blocks (2/CU)
  k_gemm_bt<64, 0, 0><<<dim3(64, 8), 256, 0, stream>>>(yh, WtP, y_out, 4096, 1024, 1024);
}